// Round 5
// baseline (372.095 us; speedup 1.0000x reference)
//
#include <hip/hip_runtime.h>
#include <stdint.h>

#define N_SEQ 4096
#define C_DIM 768
#define HEADS 12
#define HD    64
#define OI    (2304*768)

typedef __attribute__((ext_vector_type(8))) short short8;
typedef __attribute__((ext_vector_type(4))) float f32x4;
typedef __attribute__((ext_vector_type(16))) float f32x16;

__device__ __forceinline__ short f2bf(float f) {
  union { float f; unsigned u; } v; v.f = f;
  unsigned r = v.u + 0x7FFF + ((v.u >> 16) & 1);   // RNE
  return (short)(r >> 16);
}
__device__ __forceinline__ short f2bf_trunc(float f) {
  union { float f; unsigned u; } v; v.f = f;
  return (short)(v.u >> 16);                       // truncate (p>0, err<0.4%)
}

// ---------------- kernel A: combine templates -> bf16 qkv_w (2304x768) -------
__global__ __launch_bounds__(256) void prep_qkvw(const float* __restrict__ tmpl,
                                                 const float* __restrict__ coeffs,
                                                 short* __restrict__ w_bf) {
  __shared__ float c[16];
  if (threadIdx.x < 16)
    c[threadIdx.x] = 0.5f * (coeffs[threadIdx.x] + coeffs[16 + threadIdx.x]);
  __syncthreads();
  int idx = blockIdx.x * 256 + threadIdx.x;
  int base = idx * 4;
  if (base >= OI) return;
  float ax = 0.f, ay = 0.f, az = 0.f, aw = 0.f;
#pragma unroll
  for (int t = 0; t < 16; ++t) {
    float4 v = *(const float4*)(tmpl + (size_t)t * OI + base);
    float ct = c[t];
    ax = fmaf(ct, v.x, ax); ay = fmaf(ct, v.y, ay);
    az = fmaf(ct, v.z, az); aw = fmaf(ct, v.w, aw);
  }
  short4 o = make_short4(f2bf(ax), f2bf(ay), f2bf(az), f2bf(aw));
  *(short4*)(w_bf + base) = o;
}

// ---------------- kernel B: fp32 -> bf16 cast (n4 float4 groups) -------------
__global__ __launch_bounds__(256) void cvt_bf16(const float* __restrict__ src,
                                                short* __restrict__ dst, int n4) {
  int i = blockIdx.x * 256 + threadIdx.x;
  if (i >= n4) return;
  float4 v = ((const float4*)src)[i];
  ((short4*)dst)[i] = make_short4(f2bf(v.x), f2bf(v.y), f2bf(v.z), f2bf(v.w));
}

// ---------------- kernel C: 128x128 bf16 MFMA GEMM (QKV projection) ----------
// q -> [h][n][d] pre-scaled 0.125*log2e, k -> [h][n][d], v -> TRANSPOSED [h][d][n]
#define GST 40
#define QSCALE 0.1803368801111204f   // 0.125 * log2(e)
__global__ __launch_bounds__(256) void gemm_qkv(const short* __restrict__ A,
                                                const short* __restrict__ B,
                                                const float* __restrict__ bias,
                                                short* __restrict__ qkv_out) {
  __shared__ short As[128 * GST];
  __shared__ short Bs[128 * GST];
  int tid = threadIdx.x;
  int wave = tid >> 6, lane = tid & 63, g = lane >> 4, l15 = lane & 15;
  int wm = (wave >> 1) * 64, wn = (wave & 1) * 64;
  size_t mblk = (size_t)blockIdx.x * 128;
  size_t nblk = (size_t)blockIdx.y * 128;

  f32x4 acc[4][4];
#pragma unroll
  for (int mi = 0; mi < 4; ++mi)
#pragma unroll
    for (int ni = 0; ni < 4; ++ni)
#pragma unroll
      for (int r = 0; r < 4; ++r) acc[mi][ni][r] = 0.f;

  int row0 = tid >> 2;
  int c8   = (tid & 3) * 8;

  for (int k0 = 0; k0 < 768; k0 += 32) {
    short8 a0 = *(const short8*)(A + (mblk + row0) * 768 + k0 + c8);
    short8 a1 = *(const short8*)(A + (mblk + row0 + 64) * 768 + k0 + c8);
    short8 b0 = *(const short8*)(B + (nblk + row0) * 768 + k0 + c8);
    short8 b1 = *(const short8*)(B + (nblk + row0 + 64) * 768 + k0 + c8);
    __syncthreads();
    *(short8*)(As + row0 * GST + c8) = a0;
    *(short8*)(As + (row0 + 64) * GST + c8) = a1;
    *(short8*)(Bs + row0 * GST + c8) = b0;
    *(short8*)(Bs + (row0 + 64) * GST + c8) = b1;
    __syncthreads();
    short8 af[4], bfr[4];
#pragma unroll
    for (int mi = 0; mi < 4; ++mi)
      af[mi] = *(const short8*)(As + (wm + mi * 16 + l15) * GST + g * 8);
#pragma unroll
    for (int ni = 0; ni < 4; ++ni)
      bfr[ni] = *(const short8*)(Bs + (wn + ni * 16 + l15) * GST + g * 8);
#pragma unroll
    for (int mi = 0; mi < 4; ++mi)
#pragma unroll
      for (int ni = 0; ni < 4; ++ni)
        acc[mi][ni] = __builtin_amdgcn_mfma_f32_16x16x32_bf16(af[mi], bfr[ni], acc[mi][ni], 0, 0, 0);
  }

#pragma unroll
  for (int ni = 0; ni < 4; ++ni) {
    int col = (int)nblk + wn + ni * 16 + l15;
    int which = col / 768;
    int rem = col - which * 768;
    int h = rem >> 6, d = rem & 63;
    float bcol = bias[col];
    if (which == 2) {
      short* vbase = qkv_out + (size_t)2 * HEADS * N_SEQ * HD
                   + ((size_t)h * HD + d) * N_SEQ;
#pragma unroll
      for (int mi = 0; mi < 4; ++mi) {
        int rowb = (int)mblk + wm + mi * 16 + g * 4;
        short4 o;
        o.x = f2bf(acc[mi][ni][0] + bcol);
        o.y = f2bf(acc[mi][ni][1] + bcol);
        o.z = f2bf(acc[mi][ni][2] + bcol);
        o.w = f2bf(acc[mi][ni][3] + bcol);
        *(short4*)(vbase + rowb) = o;
      }
    } else {
      float sc = (which == 0) ? QSCALE : 1.0f;
      short* dst = qkv_out + ((size_t)which * HEADS + h) * N_SEQ * HD + d;
#pragma unroll
      for (int mi = 0; mi < 4; ++mi) {
        int rowb = (int)mblk + wm + mi * 16 + g * 4;
#pragma unroll
        for (int r = 0; r < 4; ++r)
          dst[(size_t)(rowb + r) * HD] = f2bf((acc[mi][ni][r] + bcol) * sc);
      }
    }
  }
}

// ---------------- kernel E: 64x64 bf16 GEMM, fp32 out + bias (proj) ----------
__global__ __launch_bounds__(256) void gemm_proj(const short* __restrict__ A,
                                                 const short* __restrict__ B,
                                                 const float* __restrict__ bias,
                                                 float* __restrict__ C) {
  __shared__ short As[64 * GST];
  __shared__ short Bs[64 * GST];
  int tid = threadIdx.x;
  int wave = tid >> 6, lane = tid & 63, g = lane >> 4, l15 = lane & 15;
  int wm = (wave >> 1) * 32, wn = (wave & 1) * 32;
  size_t mblk = (size_t)blockIdx.x * 64;
  size_t nblk = (size_t)blockIdx.y * 64;

  f32x4 acc[2][2];
#pragma unroll
  for (int mi = 0; mi < 2; ++mi)
#pragma unroll
    for (int ni = 0; ni < 2; ++ni)
#pragma unroll
      for (int r = 0; r < 4; ++r) acc[mi][ni][r] = 0.f;

  int row0 = tid >> 2;
  int c8   = (tid & 3) * 8;

  for (int k0 = 0; k0 < 768; k0 += 32) {
    short8 a0 = *(const short8*)(A + (mblk + row0) * 768 + k0 + c8);
    short8 b0 = *(const short8*)(B + (nblk + row0) * 768 + k0 + c8);
    __syncthreads();
    *(short8*)(As + row0 * GST + c8) = a0;
    *(short8*)(Bs + row0 * GST + c8) = b0;
    __syncthreads();
    short8 af[2], bfr[2];
#pragma unroll
    for (int mi = 0; mi < 2; ++mi)
      af[mi] = *(const short8*)(As + (wm + mi * 16 + l15) * GST + g * 8);
#pragma unroll
    for (int ni = 0; ni < 2; ++ni)
      bfr[ni] = *(const short8*)(Bs + (wn + ni * 16 + l15) * GST + g * 8);
#pragma unroll
    for (int mi = 0; mi < 2; ++mi)
#pragma unroll
      for (int ni = 0; ni < 2; ++ni)
        acc[mi][ni] = __builtin_amdgcn_mfma_f32_16x16x32_bf16(af[mi], bfr[ni], acc[mi][ni], 0, 0, 0);
  }

#pragma unroll
  for (int ni = 0; ni < 2; ++ni) {
    int col = (int)nblk + wn + ni * 16 + l15;
    float bcol = bias[col];
#pragma unroll
    for (int mi = 0; mi < 2; ++mi) {
      int rowb = (int)mblk + wm + mi * 16 + g * 4;
#pragma unroll
      for (int r = 0; r < 4; ++r)
        C[(size_t)(rowb + r) * 768 + col] = acc[mi][ni][r] + bcol;
    }
  }
}

// ---------------- kernel D: flash attention, kv-split partials ---------------
// 2 waves/block; wave owns 32 q-rows x one kv-half (2048). K frags loaded
// directly from global (L2-resident); V staged in LDS (shared by both waves);
// P round-trips through wave-private LDS. Static-max softmax => partial O
// (unnormalized, fp32) and partial l are additive across kv-halves.
// XCD swizzle: bid%8 -> XCD; job id sorted by head so each XCD touches <=2.5
// heads (KV working set ~2.6 MB < 4 MB per-XCD L2).
#define PST 68
__global__ __launch_bounds__(128, 3) void attn_fa(const short* __restrict__ qkv_buf,
                                                  float* __restrict__ op0,
                                                  float* __restrict__ op1,
                                                  float* __restrict__ lp) {
  __shared__ short Vt[64 * PST];    // [d][kv]
  __shared__ short Ps[2 * 32 * PST];
  int bid = blockIdx.x;
  int j = (bid & 7) * 192 + (bid >> 3);    // jobs sorted by head within XCD
  int h = j >> 7;
  int rj = j & 127;
  int half = rj >> 6;
  int qt = rj & 63;
  int tid = threadIdx.x, wave = tid >> 6, lane = tid & 63;
  int q5 = lane & 31, h5 = lane >> 5;
  int q0 = qt * 64 + wave * 32;
  int kvb = half * 2048;
  const short* qh  = qkv_buf + (size_t)(0 * HEADS + h) * N_SEQ * HD;
  const short* kh  = qkv_buf + (size_t)(1 * HEADS + h) * N_SEQ * HD;
  const short* vth = qkv_buf + (size_t)2 * HEADS * N_SEQ * HD + (size_t)h * HD * N_SEQ;

  // Q B-frags from global: n=q5, k=h5*8+j (+16c)
  short8 qf[4];
#pragma unroll
  for (int c = 0; c < 4; ++c)
    qf[c] = *(const short8*)(qh + (size_t)(q0 + q5) * HD + c * 16 + h5 * 8);

  f32x16 o_acc[2];
#pragma unroll
  for (int dt = 0; dt < 2; ++dt)
#pragma unroll
    for (int r = 0; r < 16; ++r) o_acc[dt][r] = 0.f;
  float l_r = 0.f;

  int srow = tid >> 1;            // 0..63 (d)
  int shalf = (tid & 1) * 32;     // kv half of tile

  // prefetch V tile 0
  short8 vr[4];
#pragma unroll
  for (int i = 0; i < 4; ++i)
    vr[i] = *(const short8*)(vth + (size_t)srow * N_SEQ + kvb + shalf + 8 * i);

  short* pw = Ps + wave * 32 * PST;

  for (int t0 = kvb; t0 < kvb + 2048; t0 += 64) {
    __syncthreads();
#pragma unroll
    for (int i = 0; i < 4; ++i)
      *(short8*)(Vt + srow * PST + shalf + 8 * i) = vr[i];
    __syncthreads();

    if (t0 + 64 < kvb + 2048) {
#pragma unroll
      for (int i = 0; i < 4; ++i)
        vr[i] = *(const short8*)(vth + (size_t)srow * N_SEQ + (t0 + 64) + shalf + 8 * i);
    }

    // S^T = K * Q^T : K A-frags straight from global (L2)
    f32x16 st[2];
#pragma unroll
    for (int kt = 0; kt < 2; ++kt)
#pragma unroll
      for (int r = 0; r < 16; ++r) st[kt][r] = 0.f;
#pragma unroll
    for (int c = 0; c < 4; ++c)
#pragma unroll
      for (int kt = 0; kt < 2; ++kt) {
        short8 kf = *(const short8*)(kh + (size_t)(t0 + kt * 32 + q5) * HD + c * 16 + h5 * 8);
        st[kt] = __builtin_amdgcn_mfma_f32_32x32x16_bf16(kf, qf[c], st[kt], 0, 0, 0);
      }

    // p = exp2(s); lane-local partial row-sum
#pragma unroll
    for (int kt = 0; kt < 2; ++kt)
#pragma unroll
      for (int cc = 0; cc < 4; ++cc) {
        float p0 = __builtin_amdgcn_exp2f(st[kt][cc * 4 + 0]);
        float p1 = __builtin_amdgcn_exp2f(st[kt][cc * 4 + 1]);
        float p2 = __builtin_amdgcn_exp2f(st[kt][cc * 4 + 2]);
        float p3 = __builtin_amdgcn_exp2f(st[kt][cc * 4 + 3]);
        l_r += (p0 + p1) + (p2 + p3);
        short4 o = make_short4(f2bf_trunc(p0), f2bf_trunc(p1), f2bf_trunc(p2), f2bf_trunc(p3));
        *(short4*)(pw + q5 * PST + kt * 32 + cc * 8 + h5 * 4) = o;
      }

    // O += P V
#pragma unroll
    for (int c = 0; c < 4; ++c) {
      short8 pf = *(const short8*)(pw + q5 * PST + c * 16 + h5 * 8);
#pragma unroll
      for (int dt = 0; dt < 2; ++dt) {
        short8 vf = *(const short8*)(Vt + (dt * 32 + q5) * PST + c * 16 + h5 * 8);
        o_acc[dt] = __builtin_amdgcn_mfma_f32_32x32x16_bf16(pf, vf, o_acc[dt], 0, 0, 0);
      }
    }
  }

  // combine kv-row halves (lane^32 has same q, other kv rows)
  l_r += __shfl_xor(l_r, 32);

  float* op = half ? op1 : op0;
  // o_acc[dt] reg (cc,rr) -> q=(rr+8cc+4h5), d=dt*32+q5 ; layout [h][n][d] fp32
#pragma unroll
  for (int cc = 0; cc < 4; ++cc)
#pragma unroll
    for (int rr = 0; rr < 4; ++rr) {
      int qloc = rr + 8 * cc + 4 * h5;
      size_t base = ((size_t)h * N_SEQ + q0 + qloc) * HD;
#pragma unroll
      for (int dt = 0; dt < 2; ++dt)
        op[base + dt * 32 + q5] = o_acc[dt][cc * 4 + rr];
    }
  if (h5 == 0)
    lp[((size_t)half * HEADS + h) * N_SEQ + q0 + q5] = l_r;
}

// ---------------- kernel D2: combine kv-split partials -> bf16 [n][c] --------
__global__ __launch_bounds__(256) void attn_reduce(const float* __restrict__ op0,
                                                   const float* __restrict__ op1,
                                                   const float* __restrict__ lp,
                                                   short* __restrict__ out_bf) {
  int idx = blockIdx.x * 256 + threadIdx.x;   // [12][4096][16]
  int d4 = idx & 15;
  int n  = (idx >> 4) & 4095;
  int h  = idx >> 16;
  size_t o = ((size_t)h * N_SEQ + n) * HD + d4 * 4;
  float4 a = *(const float4*)(op0 + o);
  float4 b = *(const float4*)(op1 + o);
  float l = lp[(size_t)h * N_SEQ + n] + lp[((size_t)HEADS + h) * N_SEQ + n];
  float inv = 1.0f / l;
  short4 s = make_short4(f2bf((a.x + b.x) * inv), f2bf((a.y + b.y) * inv),
                         f2bf((a.z + b.z) * inv), f2bf((a.w + b.w) * inv));
  *(short4*)(out_bf + (size_t)n * C_DIM + h * HD + d4 * 4) = s;
}

// ---------------- launcher ---------------------------------------------------
extern "C" void kernel_launch(void* const* d_in, const int* in_sizes, int n_in,
                              void* d_out, int out_size, void* d_ws, size_t ws_size,
                              hipStream_t stream) {
  const float* x        = (const float*)d_in[0];
  const float* tmpl     = (const float*)d_in[1];
  const float* coeffs   = (const float*)d_in[2];
  const float* qkv_bias = (const float*)d_in[3];
  const float* proj_w   = (const float*)d_in[4];
  const float* proj_b   = (const float*)d_in[5];
  float* out = (float*)d_out;
  char* ws = (char*)d_ws;

  short* w_bf    = (short*)(ws);                 // 2304*768
  short* x_bf    = (short*)(ws + 3538944);       // 4096*768
  short* pw_bf   = (short*)(ws + 9830400);       // 768*768
  short* qkvb    = (short*)(ws + 11010048);      // 3*12*4096*64 (v transposed)
  short* attn_bf = (short*)(ws + 29884416);      // 4096*768 bf16
  float* opart1  = (float*)(ws + 36175872);      // [12][4096][64] fp32 (12.58 MB)
  float* lpart   = (float*)(ws + 48758784);      // [2][12][4096] fp32 (0.39 MB)
  float* opart0  = out;                          // d_out reused as scratch (dead until proj)

  prep_qkvw<<<1728, 256, 0, stream>>>(tmpl, coeffs, w_bf);
  cvt_bf16<<<3072, 256, 0, stream>>>(x, x_bf, 786432);
  cvt_bf16<<<576, 256, 0, stream>>>(proj_w, pw_bf, 147456);

  dim3 g1(32, 18);
  gemm_qkv<<<g1, 256, 0, stream>>>(x_bf, w_bf, qkv_bias, qkvb);

  attn_fa<<<1536, 128, 0, stream>>>(qkvb, opart0, opart1, lpart);
  attn_reduce<<<3072, 256, 0, stream>>>(opart0, opart1, lpart, attn_bf);

  dim3 g2(64, 12);
  gemm_proj<<<g2, 256, 0, stream>>>(attn_bf, pw_bf, proj_b, out);
}

// Round 6
// 336.266 us; speedup vs baseline: 1.1066x; 1.1066x over previous
//
#include <hip/hip_runtime.h>
#include <stdint.h>

#define N_SEQ 4096
#define C_DIM 768
#define HEADS 12
#define HD    64
#define OI    (2304*768)

typedef __attribute__((ext_vector_type(8))) short short8;
typedef __attribute__((ext_vector_type(4))) float f32x4;
typedef __attribute__((ext_vector_type(16))) float f32x16;

__device__ __forceinline__ short f2bf(float f) {
  union { float f; unsigned u; } v; v.f = f;
  unsigned r = v.u + 0x7FFF + ((v.u >> 16) & 1);   // RNE
  return (short)(r >> 16);
}
__device__ __forceinline__ short f2bf_trunc(float f) {
  union { float f; unsigned u; } v; v.f = f;
  return (short)(v.u >> 16);                       // truncate (p>0, err<0.4%)
}

// ---------------- kernel A: combine templates -> bf16 qkv_w (2304x768) -------
__global__ __launch_bounds__(256) void prep_qkvw(const float* __restrict__ tmpl,
                                                 const float* __restrict__ coeffs,
                                                 short* __restrict__ w_bf) {
  __shared__ float c[16];
  if (threadIdx.x < 16)
    c[threadIdx.x] = 0.5f * (coeffs[threadIdx.x] + coeffs[16 + threadIdx.x]);
  __syncthreads();
  int idx = blockIdx.x * 256 + threadIdx.x;
  int base = idx * 4;
  if (base >= OI) return;
  float ax = 0.f, ay = 0.f, az = 0.f, aw = 0.f;
#pragma unroll
  for (int t = 0; t < 16; ++t) {
    float4 v = *(const float4*)(tmpl + (size_t)t * OI + base);
    float ct = c[t];
    ax = fmaf(ct, v.x, ax); ay = fmaf(ct, v.y, ay);
    az = fmaf(ct, v.z, az); aw = fmaf(ct, v.w, aw);
  }
  short4 o = make_short4(f2bf(ax), f2bf(ay), f2bf(az), f2bf(aw));
  *(short4*)(w_bf + base) = o;
}

// ---------------- kernel B: fp32 -> bf16 cast (n4 float4 groups) -------------
__global__ __launch_bounds__(256) void cvt_bf16(const float* __restrict__ src,
                                                short* __restrict__ dst, int n4) {
  int i = blockIdx.x * 256 + threadIdx.x;
  if (i >= n4) return;
  float4 v = ((const float4*)src)[i];
  ((short4*)dst)[i] = make_short4(f2bf(v.x), f2bf(v.y), f2bf(v.z), f2bf(v.w));
}

// ---------------- kernel C: 128x128 bf16 MFMA GEMM (QKV projection) ----------
// q -> [h][n][d] pre-scaled 0.125*log2e, k -> [h][n][d], v -> TRANSPOSED [h][d][n]
#define GST 40
#define QSCALE 0.1803368801111204f   // 0.125 * log2(e)
__global__ __launch_bounds__(256) void gemm_qkv(const short* __restrict__ A,
                                                const short* __restrict__ B,
                                                const float* __restrict__ bias,
                                                short* __restrict__ qkv_out) {
  __shared__ short As[128 * GST];
  __shared__ short Bs[128 * GST];
  int tid = threadIdx.x;
  int wave = tid >> 6, lane = tid & 63, g = lane >> 4, l15 = lane & 15;
  int wm = (wave >> 1) * 64, wn = (wave & 1) * 64;
  size_t mblk = (size_t)blockIdx.x * 128;
  size_t nblk = (size_t)blockIdx.y * 128;

  f32x4 acc[4][4];
#pragma unroll
  for (int mi = 0; mi < 4; ++mi)
#pragma unroll
    for (int ni = 0; ni < 4; ++ni)
#pragma unroll
      for (int r = 0; r < 4; ++r) acc[mi][ni][r] = 0.f;

  int row0 = tid >> 2;
  int c8   = (tid & 3) * 8;

  for (int k0 = 0; k0 < 768; k0 += 32) {
    short8 a0 = *(const short8*)(A + (mblk + row0) * 768 + k0 + c8);
    short8 a1 = *(const short8*)(A + (mblk + row0 + 64) * 768 + k0 + c8);
    short8 b0 = *(const short8*)(B + (nblk + row0) * 768 + k0 + c8);
    short8 b1 = *(const short8*)(B + (nblk + row0 + 64) * 768 + k0 + c8);
    __syncthreads();
    *(short8*)(As + row0 * GST + c8) = a0;
    *(short8*)(As + (row0 + 64) * GST + c8) = a1;
    *(short8*)(Bs + row0 * GST + c8) = b0;
    *(short8*)(Bs + (row0 + 64) * GST + c8) = b1;
    __syncthreads();
    short8 af[4], bfr[4];
#pragma unroll
    for (int mi = 0; mi < 4; ++mi)
      af[mi] = *(const short8*)(As + (wm + mi * 16 + l15) * GST + g * 8);
#pragma unroll
    for (int ni = 0; ni < 4; ++ni)
      bfr[ni] = *(const short8*)(Bs + (wn + ni * 16 + l15) * GST + g * 8);
#pragma unroll
    for (int mi = 0; mi < 4; ++mi)
#pragma unroll
      for (int ni = 0; ni < 4; ++ni)
        acc[mi][ni] = __builtin_amdgcn_mfma_f32_16x16x32_bf16(af[mi], bfr[ni], acc[mi][ni], 0, 0, 0);
  }

#pragma unroll
  for (int ni = 0; ni < 4; ++ni) {
    int col = (int)nblk + wn + ni * 16 + l15;
    int which = col / 768;
    int rem = col - which * 768;
    int h = rem >> 6, d = rem & 63;
    float bcol = bias[col];
    if (which == 2) {
      short* vbase = qkv_out + (size_t)2 * HEADS * N_SEQ * HD
                   + ((size_t)h * HD + d) * N_SEQ;
#pragma unroll
      for (int mi = 0; mi < 4; ++mi) {
        int rowb = (int)mblk + wm + mi * 16 + g * 4;
        short4 o;
        o.x = f2bf(acc[mi][ni][0] + bcol);
        o.y = f2bf(acc[mi][ni][1] + bcol);
        o.z = f2bf(acc[mi][ni][2] + bcol);
        o.w = f2bf(acc[mi][ni][3] + bcol);
        *(short4*)(vbase + rowb) = o;
      }
    } else {
      float sc = (which == 0) ? QSCALE : 1.0f;
      short* dst = qkv_out + ((size_t)which * HEADS + h) * N_SEQ * HD + d;
#pragma unroll
      for (int mi = 0; mi < 4; ++mi) {
        int rowb = (int)mblk + wm + mi * 16 + g * 4;
#pragma unroll
        for (int r = 0; r < 4; ++r)
          dst[(size_t)(rowb + r) * HD] = f2bf((acc[mi][ni][r] + bcol) * sc);
      }
    }
  }
}

// ---------------- kernel E: 64x64 bf16 GEMM, fp32 out + bias (proj) ----------
__global__ __launch_bounds__(256) void gemm_proj(const short* __restrict__ A,
                                                 const short* __restrict__ B,
                                                 const float* __restrict__ bias,
                                                 float* __restrict__ C) {
  __shared__ short As[64 * GST];
  __shared__ short Bs[64 * GST];
  int tid = threadIdx.x;
  int wave = tid >> 6, lane = tid & 63, g = lane >> 4, l15 = lane & 15;
  int wm = (wave >> 1) * 32, wn = (wave & 1) * 32;
  size_t mblk = (size_t)blockIdx.x * 64;
  size_t nblk = (size_t)blockIdx.y * 64;

  f32x4 acc[2][2];
#pragma unroll
  for (int mi = 0; mi < 2; ++mi)
#pragma unroll
    for (int ni = 0; ni < 2; ++ni)
#pragma unroll
      for (int r = 0; r < 4; ++r) acc[mi][ni][r] = 0.f;

  int row0 = tid >> 2;
  int c8   = (tid & 3) * 8;

  for (int k0 = 0; k0 < 768; k0 += 32) {
    short8 a0 = *(const short8*)(A + (mblk + row0) * 768 + k0 + c8);
    short8 b0 = *(const short8*)(B + (nblk + row0) * 768 + k0 + c8);
    __syncthreads();
    *(short8*)(As + row0 * GST + c8) = a0;
    *(short8*)(Bs + row0 * GST + c8) = b0;
    __syncthreads();
    short8 af[2], bfr[2];
#pragma unroll
    for (int mi = 0; mi < 2; ++mi)
      af[mi] = *(const short8*)(As + (wm + mi * 16 + l15) * GST + g * 8);
#pragma unroll
    for (int ni = 0; ni < 2; ++ni)
      bfr[ni] = *(const short8*)(Bs + (wn + ni * 16 + l15) * GST + g * 8);
#pragma unroll
    for (int mi = 0; mi < 2; ++mi)
#pragma unroll
      for (int ni = 0; ni < 2; ++ni)
        acc[mi][ni] = __builtin_amdgcn_mfma_f32_16x16x32_bf16(af[mi], bfr[ni], acc[mi][ni], 0, 0, 0);
  }

#pragma unroll
  for (int ni = 0; ni < 2; ++ni) {
    int col = (int)nblk + wn + ni * 16 + l15;
    float bcol = bias[col];
#pragma unroll
    for (int mi = 0; mi < 2; ++mi) {
      int rowb = (int)mblk + wm + mi * 16 + g * 4;
#pragma unroll
      for (int r = 0; r < 4; ++r)
        C[(size_t)(rowb + r) * 768 + col] = acc[mi][ni][r] + bcol;
    }
  }
}

// ---------------- kernel D: flash attention, 64q/wave, LDS-staged K&V --------
// 2 waves/block; wave owns 64 q-rows (2 subtiles of 32) x one kv-half (2048).
// K and V staged in LDS (shared by both waves); each K/V frag read feeds 2
// MFMAs (both q-subs). Transposed-S (32x32 MFMA): P stores short4, reads b128.
// Static-max softmax -> additive fp32 partials across kv-halves.
#define PST 68
__global__ __launch_bounds__(128, 2) void attn_fa(const short* __restrict__ qkv_buf,
                                                  float* __restrict__ op0,
                                                  float* __restrict__ op1,
                                                  float* __restrict__ lp) {
  __shared__ short Ks[64 * PST];    // [kv][d]
  __shared__ short Vt[64 * PST];    // [d][kv]
  __shared__ short Ps[128 * PST];   // 64 rows per wave
  int bid = blockIdx.x;
  int j = (bid & 7) * 96 + (bid >> 3);    // XCD swizzle: 96 jobs/XCD, heads clustered
  int h = j >> 6;
  int rj = j & 63;
  int half = rj >> 5;
  int qt = rj & 31;
  int tid = threadIdx.x, wave = tid >> 6, lane = tid & 63;
  int q5 = lane & 31, h5 = lane >> 5;
  int qb = qt * 128 + wave * 64;          // wave's 64-row q base
  int kvb = half * 2048;
  const short* qh  = qkv_buf + (size_t)(0 * HEADS + h) * N_SEQ * HD;
  const short* kh  = qkv_buf + (size_t)(1 * HEADS + h) * N_SEQ * HD;
  const short* vth = qkv_buf + (size_t)2 * HEADS * N_SEQ * HD + (size_t)h * HD * N_SEQ;

  // Q B-frags from global (one-time): n=q5, k=h5*8+j (+16c)
  short8 qf[2][4];
#pragma unroll
  for (int s = 0; s < 2; ++s)
#pragma unroll
    for (int c = 0; c < 4; ++c)
      qf[s][c] = *(const short8*)(qh + (size_t)(qb + s * 32 + q5) * HD + c * 16 + h5 * 8);

  f32x16 o_acc[2][2];   // [q-sub][dt]
#pragma unroll
  for (int s = 0; s < 2; ++s)
#pragma unroll
    for (int dt = 0; dt < 2; ++dt)
#pragma unroll
      for (int r = 0; r < 16; ++r) o_acc[s][dt][r] = 0.f;
  float l_r[2] = {0.f, 0.f};

  int srow = tid >> 1;            // 0..63
  int shalf = (tid & 1) * 32;

  // prefetch tile 0 (coalesced: K rows contiguous; V^T row segments 128 B)
  short8 kr[4], vr[4];
#pragma unroll
  for (int i = 0; i < 4; ++i) {
    kr[i] = *(const short8*)(kh + (size_t)(kvb + srow) * HD + shalf + 8 * i);
    vr[i] = *(const short8*)(vth + (size_t)srow * N_SEQ + kvb + shalf + 8 * i);
  }

  short* pw = Ps + wave * 64 * PST;

  for (int t0 = kvb; t0 < kvb + 2048; t0 += 64) {
    __syncthreads();
#pragma unroll
    for (int i = 0; i < 4; ++i) {
      *(short8*)(Ks + srow * PST + shalf + 8 * i) = kr[i];
      *(short8*)(Vt + srow * PST + shalf + 8 * i) = vr[i];
    }
    __syncthreads();

    if (t0 + 64 < kvb + 2048) {
      int t1 = t0 + 64;
#pragma unroll
      for (int i = 0; i < 4; ++i) {
        kr[i] = *(const short8*)(kh + (size_t)(t1 + srow) * HD + shalf + 8 * i);
        vr[i] = *(const short8*)(vth + (size_t)srow * N_SEQ + t1 + shalf + 8 * i);
      }
    }

    // S^T = K * Q^T : each kf read feeds both q-subs
    f32x16 st[2][2];    // [q-sub][kt]
#pragma unroll
    for (int s = 0; s < 2; ++s)
#pragma unroll
      for (int kt = 0; kt < 2; ++kt)
#pragma unroll
        for (int r = 0; r < 16; ++r) st[s][kt][r] = 0.f;
#pragma unroll
    for (int c = 0; c < 4; ++c)
#pragma unroll
      for (int kt = 0; kt < 2; ++kt) {
        short8 kf = *(const short8*)(Ks + (kt * 32 + q5) * PST + c * 16 + h5 * 8);
#pragma unroll
        for (int s = 0; s < 2; ++s)
          st[s][kt] = __builtin_amdgcn_mfma_f32_32x32x16_bf16(kf, qf[s][c], st[s][kt], 0, 0, 0);
      }

    // p = exp2(s); lane-local partial row-sum; P[q][kv] short4 stores
#pragma unroll
    for (int s = 0; s < 2; ++s)
#pragma unroll
      for (int kt = 0; kt < 2; ++kt)
#pragma unroll
        for (int cc = 0; cc < 4; ++cc) {
          float p0 = __builtin_amdgcn_exp2f(st[s][kt][cc * 4 + 0]);
          float p1 = __builtin_amdgcn_exp2f(st[s][kt][cc * 4 + 1]);
          float p2 = __builtin_amdgcn_exp2f(st[s][kt][cc * 4 + 2]);
          float p3 = __builtin_amdgcn_exp2f(st[s][kt][cc * 4 + 3]);
          l_r[s] += (p0 + p1) + (p2 + p3);
          short4 o = make_short4(f2bf_trunc(p0), f2bf_trunc(p1), f2bf_trunc(p2), f2bf_trunc(p3));
          *(short4*)(pw + (s * 32 + q5) * PST + kt * 32 + cc * 8 + h5 * 4) = o;
        }

    // O += P V : each vf read feeds both q-subs
#pragma unroll
    for (int c = 0; c < 4; ++c) {
      short8 pf[2];
#pragma unroll
      for (int s = 0; s < 2; ++s)
        pf[s] = *(const short8*)(pw + (s * 32 + q5) * PST + c * 16 + h5 * 8);
#pragma unroll
      for (int dt = 0; dt < 2; ++dt) {
        short8 vf = *(const short8*)(Vt + (dt * 32 + q5) * PST + c * 16 + h5 * 8);
#pragma unroll
        for (int s = 0; s < 2; ++s)
          o_acc[s][dt] = __builtin_amdgcn_mfma_f32_32x32x16_bf16(pf[s], vf, o_acc[s][dt], 0, 0, 0);
      }
    }
  }

  float* op = half ? op1 : op0;
#pragma unroll
  for (int s = 0; s < 2; ++s) {
    float l = l_r[s] + __shfl_xor(l_r[s], 32);   // combine kv-row halves
#pragma unroll
    for (int cc = 0; cc < 4; ++cc)
#pragma unroll
      for (int rr = 0; rr < 4; ++rr) {
        int qloc = rr + 8 * cc + 4 * h5;
        size_t base = ((size_t)h * N_SEQ + qb + s * 32 + qloc) * HD;
#pragma unroll
        for (int dt = 0; dt < 2; ++dt)
          op[base + dt * 32 + q5] = o_acc[s][dt][cc * 4 + rr];
      }
    if (h5 == 0)
      lp[((size_t)half * HEADS + h) * N_SEQ + qb + s * 32 + q5] = l;
  }
}

// ---------------- kernel D2: combine kv-split partials -> bf16 [n][c] --------
__global__ __launch_bounds__(256) void attn_reduce(const float* __restrict__ op0,
                                                   const float* __restrict__ op1,
                                                   const float* __restrict__ lp,
                                                   short* __restrict__ out_bf) {
  int idx = blockIdx.x * 256 + threadIdx.x;   // [12][4096][16]
  int d4 = idx & 15;
  int n  = (idx >> 4) & 4095;
  int h  = idx >> 16;
  size_t o = ((size_t)h * N_SEQ + n) * HD + d4 * 4;
  float4 a = *(const float4*)(op0 + o);
  float4 b = *(const float4*)(op1 + o);
  float l = lp[(size_t)h * N_SEQ + n] + lp[((size_t)HEADS + h) * N_SEQ + n];
  float inv = 1.0f / l;
  short4 s = make_short4(f2bf((a.x + b.x) * inv), f2bf((a.y + b.y) * inv),
                         f2bf((a.z + b.z) * inv), f2bf((a.w + b.w) * inv));
  *(short4*)(out_bf + (size_t)n * C_DIM + h * HD + d4 * 4) = s;
}

// ---------------- launcher ---------------------------------------------------
extern "C" void kernel_launch(void* const* d_in, const int* in_sizes, int n_in,
                              void* d_out, int out_size, void* d_ws, size_t ws_size,
                              hipStream_t stream) {
  const float* x        = (const float*)d_in[0];
  const float* tmpl     = (const float*)d_in[1];
  const float* coeffs   = (const float*)d_in[2];
  const float* qkv_bias = (const float*)d_in[3];
  const float* proj_w   = (const float*)d_in[4];
  const float* proj_b   = (const float*)d_in[5];
  float* out = (float*)d_out;
  char* ws = (char*)d_ws;

  short* w_bf    = (short*)(ws);                 // 2304*768
  short* x_bf    = (short*)(ws + 3538944);       // 4096*768
  short* pw_bf   = (short*)(ws + 9830400);       // 768*768
  short* qkvb    = (short*)(ws + 11010048);      // 3*12*4096*64 (v transposed)
  short* attn_bf = (short*)(ws + 29884416);      // 4096*768 bf16
  float* opart1  = (float*)(ws + 36175872);      // [12][4096][64] fp32 (12.58 MB)
  float* lpart   = (float*)(ws + 48758784);      // [2][12][4096] fp32 (0.39 MB)
  float* opart0  = out;                          // d_out reused (dead until proj)

  prep_qkvw<<<1728, 256, 0, stream>>>(tmpl, coeffs, w_bf);
  cvt_bf16<<<3072, 256, 0, stream>>>(x, x_bf, 786432);
  cvt_bf16<<<576, 256, 0, stream>>>(proj_w, pw_bf, 147456);

  dim3 g1(32, 18);
  gemm_qkv<<<g1, 256, 0, stream>>>(x_bf, w_bf, qkv_bias, qkvb);

  attn_fa<<<768, 128, 0, stream>>>(qkvb, opart0, opart1, lpart);
  attn_reduce<<<3072, 256, 0, stream>>>(opart0, opart1, lpart, attn_bf);

  dim3 g2(64, 12);
  gemm_proj<<<g2, 256, 0, stream>>>(attn_bf, pw_bf, proj_b, out);
}